// Round 1
// baseline (2116.890 us; speedup 1.0000x reference)
//
#include <hip/hip_runtime.h>
#include <math.h>

#define DIM 128
#define NEG_SLOPE 0.01f
#define L2_EPS 1e-12f

// Row L2-normalize: 32 lanes per row, float4 per lane.
__global__ __launch_bounds__(256) void normalize_kernel(
    const float* __restrict__ in, float* __restrict__ x, int n_rows) {
    int gid = blockIdx.x * blockDim.x + threadIdx.x;
    int row = gid >> 5;
    int lane = gid & 31;
    if (row >= n_rows) return;
    float4 v = reinterpret_cast<const float4*>(in + (size_t)row * DIM)[lane];
    float ss = v.x * v.x + v.y * v.y + v.z * v.z + v.w * v.w;
    #pragma unroll
    for (int m = 1; m < 32; m <<= 1) ss += __shfl_xor(ss, m, 32);
    float scale = 1.0f / fmaxf(sqrtf(ss), L2_EPS);
    float4 o = make_float4(v.x * scale, v.y * scale, v.z * scale, v.w * scale);
    reinterpret_cast<float4*>(x + (size_t)row * DIM)[lane] = o;
}

// Degree count over the doubled edge list.
// Doubled list: src[k] = ei[k] for k in [0,2E); dst[k] = ei[(k+E) % 2E].
__global__ __launch_bounds__(256) void count_kernel(
    const int* __restrict__ ei, int E, int* __restrict__ cnt) {
    int e = blockIdx.x * blockDim.x + threadIdx.x;
    if (e >= 2 * E) return;
    int dst = (e < E) ? ei[e + E] : ei[e - E];
    atomicAdd(&cnt[dst], 1);
}

// Per-edge gather * weight -> atomic scatter-add. 32 lanes per edge.
__global__ __launch_bounds__(256) void scatter_kernel(
    const float* __restrict__ xin, const int* __restrict__ ei,
    const float* __restrict__ w, float* __restrict__ sum, int E) {
    long long gid = (long long)blockIdx.x * blockDim.x + threadIdx.x;
    int e = (int)(gid >> 5);
    int lane = (int)(gid & 31);
    if (e >= 2 * E) return;
    int src = ei[e];
    int dst = (e < E) ? ei[e + E] : ei[e - E];
    float we = w[e];
    float4 v = reinterpret_cast<const float4*>(xin + (size_t)src * DIM)[lane];
    float* s = sum + (size_t)dst * DIM + lane * 4;
    unsafeAtomicAdd(s + 0, v.x * we);
    unsafeAtomicAdd(s + 1, v.y * we);
    unsafeAtomicAdd(s + 2, v.z * we);
    unsafeAtomicAdd(s + 3, v.w * we);
}

// x1 = leaky_relu(sum / max(cnt,1))
__global__ __launch_bounds__(256) void finish_kernel(
    const float* __restrict__ sum, const int* __restrict__ cnt,
    float* __restrict__ x1, int n_rows) {
    int gid = blockIdx.x * blockDim.x + threadIdx.x;
    int row = gid >> 5;
    int lane = gid & 31;
    if (row >= n_rows) return;
    float invc = 1.0f / fmaxf((float)cnt[row], 1.0f);
    float4 s = reinterpret_cast<const float4*>(sum + (size_t)row * DIM)[lane];
    float4 o;
    o.x = s.x * invc; o.x = o.x > 0.f ? o.x : NEG_SLOPE * o.x;
    o.y = s.y * invc; o.y = o.y > 0.f ? o.y : NEG_SLOPE * o.y;
    o.z = s.z * invc; o.z = o.z > 0.f ? o.z : NEG_SLOPE * o.z;
    o.w = s.w * invc; o.w = o.w > 0.f ? o.w : NEG_SLOPE * o.w;
    reinterpret_cast<float4*>(x1 + (size_t)row * DIM)[lane] = o;
}

// out = x (already in d_out) + x1 + leaky_relu(sum / max(cnt,1))
__global__ __launch_bounds__(256) void final_kernel(
    float* __restrict__ out, const float* __restrict__ x1,
    const float* __restrict__ sum, const int* __restrict__ cnt, int n_rows) {
    int gid = blockIdx.x * blockDim.x + threadIdx.x;
    int row = gid >> 5;
    int lane = gid & 31;
    if (row >= n_rows) return;
    float invc = 1.0f / fmaxf((float)cnt[row], 1.0f);
    size_t off = (size_t)row * DIM;
    float4 s = reinterpret_cast<const float4*>(sum + off)[lane];
    float4 a = reinterpret_cast<const float4*>(x1 + off)[lane];
    float4 xv = reinterpret_cast<const float4*>(out + off)[lane];
    float4 o;
    float t;
    t = s.x * invc; t = t > 0.f ? t : NEG_SLOPE * t; o.x = xv.x + a.x + t;
    t = s.y * invc; t = t > 0.f ? t : NEG_SLOPE * t; o.y = xv.y + a.y + t;
    t = s.z * invc; t = t > 0.f ? t : NEG_SLOPE * t; o.z = xv.z + a.z + t;
    t = s.w * invc; t = t > 0.f ? t : NEG_SLOPE * t; o.w = xv.w + a.w + t;
    reinterpret_cast<float4*>(out + off)[lane] = o;
}

extern "C" void kernel_launch(void* const* d_in, const int* in_sizes, int n_in,
                              void* d_out, int out_size, void* d_ws, size_t ws_size,
                              hipStream_t stream) {
    const float* id_emb = (const float*)d_in[0];
    const int* ei = (const int*)d_in[1];
    const float* w = (const float*)d_in[2];
    float* out = (float*)d_out;

    const int N = in_sizes[0] / DIM;      // 100000
    const int E = in_sizes[1] / 2;        // 300000
    const size_t ND = (size_t)N * DIM;

    float* x1 = (float*)d_ws;                 // N*D floats
    float* sum = x1 + ND;                     // N*D floats
    int* cnt = (int*)(sum + ND);              // N ints

    // zero cnt + sum
    hipMemsetAsync(cnt, 0, (size_t)N * sizeof(int), stream);
    hipMemsetAsync(sum, 0, ND * sizeof(float), stream);

    // x = normalize(id_emb) -> stored in d_out
    {
        int total = N * 32;
        int blocks = (total + 255) / 256;
        normalize_kernel<<<blocks, 256, 0, stream>>>(id_emb, out, N);
    }
    // degree counts
    {
        int total = 2 * E;
        int blocks = (total + 255) / 256;
        count_kernel<<<blocks, 256, 0, stream>>>(ei, E, cnt);
    }
    // conv1 scatter: x (in d_out) -> sum
    {
        long long total = (long long)2 * E * 32;
        int blocks = (int)((total + 255) / 256);
        scatter_kernel<<<blocks, 256, 0, stream>>>(out, ei, w, sum, E);
    }
    // x1 = leaky(sum/cnt)
    {
        int total = N * 32;
        int blocks = (total + 255) / 256;
        finish_kernel<<<blocks, 256, 0, stream>>>(sum, cnt, x1, N);
    }
    // conv2: zero sum, scatter x1 -> sum
    hipMemsetAsync(sum, 0, ND * sizeof(float), stream);
    {
        long long total = (long long)2 * E * 32;
        int blocks = (int)((total + 255) / 256);
        scatter_kernel<<<blocks, 256, 0, stream>>>(x1, ei, w, sum, E);
    }
    // out = x + x1 + leaky(sum/cnt)
    {
        int total = N * 32;
        int blocks = (total + 255) / 256;
        final_kernel<<<blocks, 256, 0, stream>>>(out, x1, sum, cnt, N);
    }
}

// Round 2
// 208.741 us; speedup vs baseline: 10.1412x; 10.1412x over previous
//
#include <hip/hip_runtime.h>
#include <math.h>

#define DIM 128
#define NEG_SLOPE 0.01f
#define L2_EPS 1e-12f

// ---------- Row L2-normalize: 32 lanes per row, float4 per lane ----------
__global__ __launch_bounds__(256) void normalize_kernel(
    const float* __restrict__ in, float* __restrict__ x, int n_rows) {
    int gid = blockIdx.x * blockDim.x + threadIdx.x;
    int row = gid >> 5;
    int lane = gid & 31;
    if (row >= n_rows) return;
    float4 v = reinterpret_cast<const float4*>(in + (size_t)row * DIM)[lane];
    float ss = v.x * v.x + v.y * v.y + v.z * v.z + v.w * v.w;
    #pragma unroll
    for (int m = 1; m < 32; m <<= 1) ss += __shfl_xor(ss, m, 32);
    float scale = 1.0f / fmaxf(sqrtf(ss), L2_EPS);
    float4 o = make_float4(v.x * scale, v.y * scale, v.z * scale, v.w * scale);
    reinterpret_cast<float4*>(x + (size_t)row * DIM)[lane] = o;
}

// ---------- CSR build ----------
// Doubled edge list: src[k] = ei[k], dst[k] = ei[(k+E) mod 2E], k in [0,2E).
__global__ __launch_bounds__(256) void hist_kernel(
    const int* __restrict__ ei, int E, int* __restrict__ cnt) {
    int e = blockIdx.x * blockDim.x + threadIdx.x;
    if (e >= 2 * E) return;
    int dst = (e < E) ? ei[e + E] : ei[e - E];
    atomicAdd(&cnt[dst], 1);
}

// Block-level exclusive scan: 256 threads x 4 items = 1024 per block.
__global__ __launch_bounds__(256) void scan_block_kernel(
    const int* __restrict__ cnt, int* __restrict__ excl,
    int* __restrict__ blocksums, int n) {
    __shared__ int sdata[256];
    int t = threadIdx.x;
    int base = blockIdx.x * 1024 + t * 4;
    int v0 = 0, v1 = 0, v2 = 0, v3 = 0;
    if (base + 0 < n) v0 = cnt[base + 0];
    if (base + 1 < n) v1 = cnt[base + 1];
    if (base + 2 < n) v2 = cnt[base + 2];
    if (base + 3 < n) v3 = cnt[base + 3];
    int tsum = v0 + v1 + v2 + v3;
    sdata[t] = tsum;
    __syncthreads();
    #pragma unroll
    for (int off = 1; off < 256; off <<= 1) {
        int val = (t >= off) ? sdata[t - off] : 0;
        __syncthreads();
        sdata[t] += val;
        __syncthreads();
    }
    int texcl = sdata[t] - tsum;  // exclusive prefix of this thread within block
    if (t == 255) blocksums[blockIdx.x] = sdata[255];
    if (base + 0 < n) excl[base + 0] = texcl;
    if (base + 1 < n) excl[base + 1] = texcl + v0;
    if (base + 2 < n) excl[base + 2] = texcl + v0 + v1;
    if (base + 3 < n) excl[base + 3] = texcl + v0 + v1 + v2;
}

// Exclusive scan of up to 128 block sums in a single 64-lane wave.
__global__ __launch_bounds__(64) void scan_sums_kernel(int* __restrict__ bs, int nb) {
    int l = threadIdx.x;
    int v0 = (2 * l < nb) ? bs[2 * l] : 0;
    int v1 = (2 * l + 1 < nb) ? bs[2 * l + 1] : 0;
    int s = v0 + v1;
    #pragma unroll
    for (int off = 1; off < 64; off <<= 1) {
        int u = __shfl_up(s, off, 64);
        if (l >= off) s += u;
    }
    int excl = s - (v0 + v1);
    if (2 * l < nb) bs[2 * l] = excl;
    if (2 * l + 1 < nb) bs[2 * l + 1] = excl + v0;
}

__global__ __launch_bounds__(256) void add_base_kernel(
    int* __restrict__ rowptr, int* __restrict__ cursor,
    const int* __restrict__ blocksums, int n) {
    int i = blockIdx.x * blockDim.x + threadIdx.x;
    if (i >= n) return;
    int v = rowptr[i] + blocksums[i >> 10];
    rowptr[i] = v;
    cursor[i] = v;
}

// Fill CSR buckets with packed {src, w} pairs.
__global__ __launch_bounds__(256) void fill_kernel(
    const int* __restrict__ ei, const float* __restrict__ w,
    int* __restrict__ cursor, int2* __restrict__ epair, int E) {
    int e = blockIdx.x * blockDim.x + threadIdx.x;
    if (e >= 2 * E) return;
    int src = ei[e];
    int dst = (e < E) ? ei[e + E] : ei[e - E];
    int pos = atomicAdd(&cursor[dst], 1);
    epair[pos] = make_int2(src, __float_as_int(w[e]));
}

// ---------- Node-parallel gather-reduce conv ----------
// MODE 0: x1[row] = leaky(acc / max(deg,1))
// MODE 1: out[row] = out[row](=x) + add1[row](=x1) + leaky(acc / max(deg,1))
template <int MODE>
__global__ __launch_bounds__(256) void conv_kernel(
    const float* __restrict__ xin, const int* __restrict__ rowptr,
    const int* __restrict__ cnt, const int2* __restrict__ epair,
    float* __restrict__ x1, const float* __restrict__ add1,
    float* __restrict__ out, int n_rows) {
    int gid = blockIdx.x * blockDim.x + threadIdx.x;
    int row = gid >> 5;
    int lane = gid & 31;
    if (row >= n_rows) return;
    int start = rowptr[row];
    int deg = cnt[row];
    float4 acc = make_float4(0.f, 0.f, 0.f, 0.f);
    for (int k = start; k < start + deg; ++k) {
        int2 p = epair[k];
        float we = __int_as_float(p.y);
        float4 v = reinterpret_cast<const float4*>(xin + (size_t)p.x * DIM)[lane];
        acc.x += v.x * we;
        acc.y += v.y * we;
        acc.z += v.z * we;
        acc.w += v.w * we;
    }
    float invc = 1.0f / fmaxf((float)deg, 1.0f);
    float4 t;
    t.x = acc.x * invc; t.x = t.x > 0.f ? t.x : NEG_SLOPE * t.x;
    t.y = acc.y * invc; t.y = t.y > 0.f ? t.y : NEG_SLOPE * t.y;
    t.z = acc.z * invc; t.z = t.z > 0.f ? t.z : NEG_SLOPE * t.z;
    t.w = acc.w * invc; t.w = t.w > 0.f ? t.w : NEG_SLOPE * t.w;
    size_t off = (size_t)row * DIM;
    if (MODE == 0) {
        reinterpret_cast<float4*>(x1 + off)[lane] = t;
    } else {
        float4 xv = reinterpret_cast<const float4*>(out + off)[lane];
        float4 a = reinterpret_cast<const float4*>(add1 + off)[lane];
        t.x += xv.x + a.x;
        t.y += xv.y + a.y;
        t.z += xv.z + a.z;
        t.w += xv.w + a.w;
        reinterpret_cast<float4*>(out + off)[lane] = t;
    }
}

extern "C" void kernel_launch(void* const* d_in, const int* in_sizes, int n_in,
                              void* d_out, int out_size, void* d_ws, size_t ws_size,
                              hipStream_t stream) {
    const float* id_emb = (const float*)d_in[0];
    const int* ei = (const int*)d_in[1];
    const float* w = (const float*)d_in[2];
    float* out = (float*)d_out;

    const int N = in_sizes[0] / DIM;      // 100000
    const int E = in_sizes[1] / 2;        // 300000
    const size_t ND = (size_t)N * DIM;

    // workspace layout
    float* x1 = (float*)d_ws;                       // ND floats
    int* rowptr = (int*)(x1 + ND);                  // N ints
    int* cursor = rowptr + N;                       // N ints
    int* cnt = cursor + N;                          // N ints
    int* blocksums = cnt + N;                       // up to 128 ints
    int2* epair = (int2*)(blocksums + 128);         // 2E int2

    const int nscan = (N + 1023) / 1024;

    hipMemsetAsync(cnt, 0, (size_t)N * sizeof(int), stream);

    // x = normalize(id_emb) -> d_out
    normalize_kernel<<<(N * 32 + 255) / 256, 256, 0, stream>>>(id_emb, out, N);

    // CSR build
    hist_kernel<<<(2 * E + 255) / 256, 256, 0, stream>>>(ei, E, cnt);
    scan_block_kernel<<<nscan, 256, 0, stream>>>(cnt, rowptr, blocksums, N);
    scan_sums_kernel<<<1, 64, 0, stream>>>(blocksums, nscan);
    add_base_kernel<<<(N + 255) / 256, 256, 0, stream>>>(rowptr, cursor, blocksums, N);
    fill_kernel<<<(2 * E + 255) / 256, 256, 0, stream>>>(ei, w, cursor, epair, E);

    // conv1: gather x (d_out) -> x1
    conv_kernel<0><<<(N * 32 + 255) / 256, 256, 0, stream>>>(
        out, rowptr, cnt, epair, x1, nullptr, nullptr, N);
    // conv2 + final fusion: out = x + x1 + leaky(mean)
    conv_kernel<1><<<(N * 32 + 255) / 256, 256, 0, stream>>>(
        x1, rowptr, cnt, epair, nullptr, x1, out, N);
}